// Round 13
// baseline (278.902 us; speedup 1.0000x reference)
//
#include <hip/hip_runtime.h>
#include <math.h>

#define BATCH 1024
#define TT    128
#define NBI   13
#define HH    128
#define T_INP 64
#define BB    2            // batch elements per block
#define NBLK  (BATCH/BB)   // 512 blocks -> 2 co-resident blocks per CU
#define NTHR  1024         // 16 waves; 60-VGPR codegen (R12) -> 32 waves/CU fits

#define LOG2E 1.4426950408889634f
#define C2L   2.8853900817779268f   // 2*log2e  (c-state scale)
#define C4L   5.7707801635558537f   // 4*log2e

typedef _Float16 half8 __attribute__((ext_vector_type(8)));
typedef float    f32x4 __attribute__((ext_vector_type(4)));

__device__ __forceinline__ unsigned short f16b(float v) {
    return __builtin_bit_cast(unsigned short, (_Float16)v);
}
__device__ __forceinline__ float rcpf_(float x) { return __builtin_amdgcn_rcpf(x); }

#if __has_builtin(__builtin_amdgcn_exp2f)
__device__ __forceinline__ float exp2_(float x) { return __builtin_amdgcn_exp2f(x); }
#else
__device__ __forceinline__ float exp2_(float x) { return __expf(x * 0.6931471805599453f); }
#endif

// light barrier: LDS visibility only — never drain vmcnt in the step loop
__device__ __forceinline__ void barrier_lds() {
    asm volatile("s_waitcnt lgkmcnt(0)" ::: "memory");
    __builtin_amdgcn_sched_barrier(0);
    __builtin_amdgcn_s_barrier();
    __builtin_amdgcn_sched_barrier(0);
}

// ---- ws layout (bytes) ----
// gate rows pre-scaled: i/f/o rows by -log2e, g rows by +2*log2e.
#define WS_WHH   0            // ushort[512*128] teacher W_hh (f16, scaled)
#define WS_WHAT  131072       // ushort[512*128] folded W^ (f16, scaled)
#define WS_WIHP  262144       // ushort[512*32]  W_ih padded 13->32 (f16, scaled)
#define WS_WOUT  294912       // ushort[16*128]  W_out padded 13->16 rows (f16)
#define WS_BT    299008       // float[512] teacher bias (scaled)
#define WS_BA    301056       // float[512] auto bias (scaled)

__global__ void fold_kernel(const float* __restrict__ W_ih,
                            const float* __restrict__ W_hh,
                            const float* __restrict__ b_ih,
                            const float* __restrict__ b_hh,
                            const float* __restrict__ W_out,
                            const float* __restrict__ b_out,
                            unsigned char* __restrict__ ws)
{
    const int j = blockIdx.x;   // gate row 0..511
    const int k = threadIdx.x;  // hidden col 0..127
    unsigned short* whh16  = (unsigned short*)(ws + WS_WHH);
    unsigned short* what16 = (unsigned short*)(ws + WS_WHAT);
    unsigned short* wihp16 = (unsigned short*)(ws + WS_WIHP);
    unsigned short* wout16 = (unsigned short*)(ws + WS_WOUT);
    float* bias_t = (float*)(ws + WS_BT);
    float* bias_a = (float*)(ws + WS_BA);

    const int gate = j >> 7;
    const float sc = (gate == 2) ? (2.0f * LOG2E) : (-LOG2E);

    float whh = W_hh[j * HH + k];
    float acc = whh;
#pragma unroll
    for (int m = 0; m < NBI; ++m)
        acc += W_ih[j * NBI + m] * W_out[m * HH + k];
    whh16[j * HH + k]  = f16b(sc * whh);
    what16[j * HH + k] = f16b(sc * acc);

    if (k < 32) wihp16[j * 32 + k] = (k < NBI) ? f16b(sc * W_ih[j * NBI + k]) : (unsigned short)0;
    if (k == 0) {
        float bt = b_ih[j] + b_hh[j];
        bias_t[j] = sc * bt;
        float ba = bt;
#pragma unroll
        for (int m = 0; m < NBI; ++m) ba += W_ih[j * NBI + m] * b_out[m];
        bias_a[j] = sc * ba;
    }
    if (j < 16) wout16[j * HH + k] = (j < NBI) ? f16b(W_out[j * HH + k]) : (unsigned short)0;
}

#define MFMA16(A, B, C) __builtin_amdgcn_mfma_f32_16x16x32_f16((A), (B), (C), 0, 0, 0)

__global__ __launch_bounds__(NTHR, 2)
void lstm_main(const float* __restrict__ x,
               const float* __restrict__ b_out,
               const unsigned char* __restrict__ ws,
               float* __restrict__ out)
{
    const int j  = threadIdx.x;   // 0..1023, 16 waves
    const int w  = j >> 6;        // wave 0..15 : owns gate rows [32w, 32w+32)
    const int l  = j & 63;
    const int q  = l >> 4;        // lane k-group / D row-group
    const int cb = l & 15;        // B col (batch; valid < BB) / A row within tile
    const int bbase = blockIdx.x * BB;

    const unsigned short* whh16  = (const unsigned short*)(ws + WS_WHH);
    const unsigned short* what16 = (const unsigned short*)(ws + WS_WHAT);
    const unsigned short* wihp16 = (const unsigned short*)(ws + WS_WIHP);
    const unsigned short* wout16 = (const unsigned short*)(ws + WS_WOUT);
    const float* btfp = (const float*)(ws + WS_BT);
    const float* bafp = (const float*)(ws + WS_BA);

    // padded LDS: 17-granule rows / 520-float g-stride (all accesses <=2-way).
    // Pad col 16 never written (stays 0) = broadcast target for invalid cols.
    __shared__ half8 h_s[2][16][17];   // h state (f16), k = 8*kc + i
    __shared__ half8 x_s[2][4][17];    // x_t padded to K=32
    __shared__ float g_sf[BB * 520];   // raw gate exchange: [b][512 rows + pad]

    const int cbn = (cb < BB) ? cb : 16;

    // ---- register fragments: wave w -> tiles a=0,1: rows 32w+16a+cb ----
    half8 wf[2][4];
    half8 wxf[2];
    half8 wof[4];
    f32x4 binit[2];
#pragma unroll
    for (int a = 0; a < 2; ++a) {
        const int row = 32 * w + 16 * a + cb;
#pragma unroll
        for (int kk = 0; kk < 4; ++kk)
            wf[a][kk] = *(const half8*)(whh16 + row * HH + 32 * kk + 8 * q);
        wxf[a] = *(const half8*)(wihp16 + row * 32 + 8 * q);
#pragma unroll
        for (int r = 0; r < 4; ++r)
            binit[a][r] = btfp[32 * w + 16 * a + 4 * q + r];
    }
    const bool projw = (w == 14);      // threads 0-255 do U; wave 15 stages x
#pragma unroll
    for (int kk = 0; kk < 4; ++kk)
        wof[kk] = *(const half8*)(wout16 + cb * HH + 32 * kk + 8 * q);

    f32x4 bo4;
#pragma unroll
    for (int r = 0; r < 4; ++r) {
        const int m = 4 * q + r;
        bo4[r] = (m < NBI) ? b_out[m] : 0.0f;
    }
    const f32x4 z4 = {0.f, 0.f, 0.f, 0.f};
    float* pob = out + (size_t)(bbase + (cb & (BB - 1))) * TT * NBI;  // proj base (guard cb<BB)

    // ---- U-phase mapping: threads 0..128*BB-1, 1 cell update each ----
    const bool doU = (j < 128 * BB);
    const int uu = j & 127;           // hidden unit
    const int ub = (j >> 7) & (BB - 1);   // batch within block
    const float* gme = g_sf + ub * 520 + uu;

    // ---- x staging role: wave 15, BB*NBI lanes ----
    const int  sid = j - 960;
    const bool stg = (sid >= 0) && (sid < BB * NBI);
    int s_b = 0, s_m = 0;
    const float* xp0 = x;
    float xa_h = 0.f;
    if (stg) { s_b = sid / 13; s_m = sid - 13 * s_b;
               xp0 = x + (size_t)(bbase + s_b) * TT * NBI + s_m; }

    // ---- init LDS: zero everything (pads stay 0 forever) ----
    {
        half8* hz = (half8*)h_s;              // 2*16*17 = 544 granules
        if (j < 544) hz[j] = (half8)(_Float16)0.0f;
        half8* xz = (half8*)x_s;              // 2*4*17 = 136 granules
        if (j < 136) xz[j] = (half8)(_Float16)0.0f;
    }
    __syncthreads();
    if (stg) {
        float v = xp0[0];                                     // x[b][0][m]
        ((_Float16*)&x_s[0][s_m >> 3][s_b])[s_m & 7] = (_Float16)v;
        out[(size_t)(bbase + s_b) * TT * NBI + s_m] = v;      // out[:,0,:] = x[:,0,:]
        xa_h = xp0[NBI];                                      // x[b][1][m]
    }
    __syncthreads();

    float c = 0.0f;        // c state pre-scaled by 2*log2e (1 per U-thread)
    int cur = 0;

    // ================= teacher phase: t = 0 .. T_INP =================
    for (int t = 0; t <= T_INP; ++t) {
        const int nxt = cur ^ 1;

        float xa_p = 0.f;
        if (stg && t + 2 <= T_INP) xa_p = xp0[(t + 2) * NBI];

        // ---- G phase (invalid cols broadcast the zero pad granule) ----
        half8 xf  = x_s[cur][q][cbn];
        half8 hb0 = h_s[cur][q][cbn];
        half8 hb1 = h_s[cur][4 + q][cbn];
        half8 hb2 = h_s[cur][8 + q][cbn];
        half8 hb3 = h_s[cur][12 + q][cbn];

        f32x4 a0 = MFMA16(wxf[0], xf, binit[0]);
        f32x4 a1 = MFMA16(wxf[1], xf, binit[1]);
        a0 = MFMA16(wf[0][0], hb0, a0); a1 = MFMA16(wf[1][0], hb0, a1);
        a0 = MFMA16(wf[0][1], hb1, a0); a1 = MFMA16(wf[1][1], hb1, a1);
        a0 = MFMA16(wf[0][2], hb2, a0); a1 = MFMA16(wf[1][2], hb2, a1);
        a0 = MFMA16(wf[0][3], hb3, a0); a1 = MFMA16(wf[1][3], hb3, a1);

        f32x4 pacc = z4;
        if (projw) {
            pacc = MFMA16(wof[0], hb0, z4);
            pacc = MFMA16(wof[1], hb1, pacc);
            pacc = MFMA16(wof[2], hb2, pacc);
            pacc = MFMA16(wof[3], hb3, pacc);
        }

        // raw gate exchange (stride 520 -> <=2-way banks)
        if (cb < BB) {
            float* gb = g_sf + cb * 520 + 32 * w + 4 * q;
            *(f32x4*)(gb)      = a0;
            *(f32x4*)(gb + 16) = a1;
        }
        if (projw && t >= 1 && cb < BB) {
#pragma unroll
            for (int r = 0; r < 4; ++r) {
                const int m = 4 * q + r;
                if (m < NBI) pob[t * NBI + m] = pacc[r] + bo4[r];
            }
        }
        barrier_lds();

        // ---- U phase: threads 0..128*BB-1, 1 dense cell update each ----
        if (doU) {
            float gi = gme[0], gf = gme[128], gg = gme[256], go = gme[384];
            float ig = rcpf_(1.0f + exp2_(gi));
            float fg = rcpf_(1.0f + exp2_(gf));
            float rg = rcpf_(exp2_(gg) + 1.0f);
            float gp = C2L - C4L * rg;               // 2log2e * tanh(g)
            float og = rcpf_(1.0f + exp2_(go));
            float cn = fg * c + ig * gp;
            c = cn;
            float ec = exp2_(cn);
            float hv = og * (1.0f - 2.0f * rcpf_(ec + 1.0f));
            ((_Float16*)&h_s[nxt][uu >> 3][ub])[uu & 7] = (_Float16)hv;
        }
        if (stg && t + 1 <= T_INP) {
            ((_Float16*)&x_s[nxt][s_m >> 3][s_b])[s_m & 7] = (_Float16)xa_h;
            xa_h = xa_p;
        }
        barrier_lds();
        cur = nxt;
    }

    // ---- switch to folded weights / auto bias (uniform) ----
#pragma unroll
    for (int a = 0; a < 2; ++a) {
        const int row = 32 * w + 16 * a + cb;
#pragma unroll
        for (int kk = 0; kk < 4; ++kk)
            wf[a][kk] = *(const half8*)(what16 + row * HH + 32 * kk + 8 * q);
#pragma unroll
        for (int r = 0; r < 4; ++r)
            binit[a][r] = bafp[32 * w + 16 * a + 4 * q + r];
    }

    // ================= auto phase: t = T_INP+1 .. TT-2 =================
    for (int t = T_INP + 1; t < TT - 1; ++t) {
        const int nxt = cur ^ 1;

        half8 hb0 = h_s[cur][q][cbn];
        half8 hb1 = h_s[cur][4 + q][cbn];
        half8 hb2 = h_s[cur][8 + q][cbn];
        half8 hb3 = h_s[cur][12 + q][cbn];

        f32x4 a0 = MFMA16(wf[0][0], hb0, binit[0]);
        f32x4 a1 = MFMA16(wf[1][0], hb0, binit[1]);
        a0 = MFMA16(wf[0][1], hb1, a0); a1 = MFMA16(wf[1][1], hb1, a1);
        a0 = MFMA16(wf[0][2], hb2, a0); a1 = MFMA16(wf[1][2], hb2, a1);
        a0 = MFMA16(wf[0][3], hb3, a0); a1 = MFMA16(wf[1][3], hb3, a1);

        f32x4 pacc = z4;
        if (projw) {
            pacc = MFMA16(wof[0], hb0, z4);
            pacc = MFMA16(wof[1], hb1, pacc);
            pacc = MFMA16(wof[2], hb2, pacc);
            pacc = MFMA16(wof[3], hb3, pacc);
        }

        if (cb < BB) {
            float* gb = g_sf + cb * 520 + 32 * w + 4 * q;
            *(f32x4*)(gb)      = a0;
            *(f32x4*)(gb + 16) = a1;
        }
        if (projw && cb < BB) {
#pragma unroll
            for (int r = 0; r < 4; ++r) {
                const int m = 4 * q + r;
                if (m < NBI) pob[t * NBI + m] = pacc[r] + bo4[r];
            }
        }
        barrier_lds();

        if (doU) {
            float gi = gme[0], gf = gme[128], gg = gme[256], go = gme[384];
            float ig = rcpf_(1.0f + exp2_(gi));
            float fg = rcpf_(1.0f + exp2_(gf));
            float rg = rcpf_(exp2_(gg) + 1.0f);
            float gp = C2L - C4L * rg;
            float og = rcpf_(1.0f + exp2_(go));
            float cn = fg * c + ig * gp;
            c = cn;
            float ec = exp2_(cn);
            float hv = og * (1.0f - 2.0f * rcpf_(ec + 1.0f));
            ((_Float16*)&h_s[nxt][uu >> 3][ub])[uu & 7] = (_Float16)hv;
        }
        barrier_lds();
        cur = nxt;
    }

    // ---- epilogue: out[127] = W_out h^127 + b_out ----
    if (projw) {
        half8 hb0 = h_s[cur][q][cbn];
        half8 hb1 = h_s[cur][4 + q][cbn];
        half8 hb2 = h_s[cur][8 + q][cbn];
        half8 hb3 = h_s[cur][12 + q][cbn];
        f32x4 pacc = MFMA16(wof[0], hb0, z4);
        pacc = MFMA16(wof[1], hb1, pacc);
        pacc = MFMA16(wof[2], hb2, pacc);
        pacc = MFMA16(wof[3], hb3, pacc);
        if (cb < BB) {
#pragma unroll
            for (int r = 0; r < 4; ++r) {
                const int m = 4 * q + r;
                if (m < NBI) pob[(TT - 1) * NBI + m] = pacc[r] + bo4[r];
            }
        }
    }
}

extern "C" void kernel_launch(void* const* d_in, const int* in_sizes, int n_in,
                              void* d_out, int out_size, void* d_ws, size_t ws_size,
                              hipStream_t stream)
{
    const float* x     = (const float*)d_in[0];
    const float* W_ih  = (const float*)d_in[1];
    const float* W_hh  = (const float*)d_in[2];
    const float* b_ih  = (const float*)d_in[3];
    const float* b_hh  = (const float*)d_in[4];
    const float* W_out = (const float*)d_in[5];
    const float* b_out = (const float*)d_in[6];
    float* out = (float*)d_out;
    unsigned char* ws = (unsigned char*)d_ws;

    fold_kernel<<<512, HH, 0, stream>>>(W_ih, W_hh, b_ih, b_hh, W_out, b_out, ws);
    lstm_main<<<NBLK, NTHR, 0, stream>>>(x, b_out, ws, out);
}

// Round 14
// 173.963 us; speedup vs baseline: 1.6032x; 1.6032x over previous
//
#include <hip/hip_runtime.h>
#include <math.h>

#define BATCH 1024
#define TT    128
#define NBI   13
#define HH    128
#define T_INP 64
#define BB    4            // batch elements per block
#define NBLK  (BATCH/BB)   // 256 blocks -> all CUs

#define LOG2E 1.4426950408889634f
#define C2L   2.8853900817779268f   // 2*log2e  (c-state scale)
#define C4L   5.7707801635558537f   // 4*log2e

typedef _Float16 half8 __attribute__((ext_vector_type(8)));
typedef float    f32x4 __attribute__((ext_vector_type(4)));

__device__ __forceinline__ unsigned short f16b(float v) {
    return __builtin_bit_cast(unsigned short, (_Float16)v);
}
__device__ __forceinline__ float rcpf_(float x) { return __builtin_amdgcn_rcpf(x); }

#if __has_builtin(__builtin_amdgcn_exp2f)
__device__ __forceinline__ float exp2_(float x) { return __builtin_amdgcn_exp2f(x); }
#else
__device__ __forceinline__ float exp2_(float x) { return __expf(x * 0.6931471805599453f); }
#endif

// light barrier: LDS visibility only — never drain vmcnt in the step loop
__device__ __forceinline__ void barrier_lds() {
    asm volatile("s_waitcnt lgkmcnt(0)" ::: "memory");
    __builtin_amdgcn_sched_barrier(0);
    __builtin_amdgcn_s_barrier();
    __builtin_amdgcn_sched_barrier(0);
}

// ---- ws layout (bytes) ----
// gate rows pre-scaled: i/f/o rows by -log2e, g rows by +2*log2e.
#define WS_WHH   0            // ushort[512*128] teacher W_hh (f16, scaled)
#define WS_WHAT  131072       // ushort[512*128] folded W^ (f16, scaled)
#define WS_WIHP  262144       // ushort[512*32]  W_ih padded 13->32 (f16, scaled)
#define WS_WOUT  294912       // ushort[16*128]  W_out padded 13->16 rows (f16)
#define WS_BT    299008       // float[512] teacher bias (scaled)
#define WS_BA    301056       // float[512] auto bias (scaled)

__global__ void fold_kernel(const float* __restrict__ W_ih,
                            const float* __restrict__ W_hh,
                            const float* __restrict__ b_ih,
                            const float* __restrict__ b_hh,
                            const float* __restrict__ W_out,
                            const float* __restrict__ b_out,
                            unsigned char* __restrict__ ws)
{
    const int j = blockIdx.x;   // gate row 0..511
    const int k = threadIdx.x;  // hidden col 0..127
    unsigned short* whh16  = (unsigned short*)(ws + WS_WHH);
    unsigned short* what16 = (unsigned short*)(ws + WS_WHAT);
    unsigned short* wihp16 = (unsigned short*)(ws + WS_WIHP);
    unsigned short* wout16 = (unsigned short*)(ws + WS_WOUT);
    float* bias_t = (float*)(ws + WS_BT);
    float* bias_a = (float*)(ws + WS_BA);

    const int gate = j >> 7;
    const float sc = (gate == 2) ? (2.0f * LOG2E) : (-LOG2E);

    float whh = W_hh[j * HH + k];
    float acc = whh;
#pragma unroll
    for (int m = 0; m < NBI; ++m)
        acc += W_ih[j * NBI + m] * W_out[m * HH + k];
    whh16[j * HH + k]  = f16b(sc * whh);
    what16[j * HH + k] = f16b(sc * acc);

    if (k < 32) wihp16[j * 32 + k] = (k < NBI) ? f16b(sc * W_ih[j * NBI + k]) : (unsigned short)0;
    if (k == 0) {
        float bt = b_ih[j] + b_hh[j];
        bias_t[j] = sc * bt;
        float ba = bt;
#pragma unroll
        for (int m = 0; m < NBI; ++m) ba += W_ih[j * NBI + m] * b_out[m];
        bias_a[j] = sc * ba;
    }
    if (j < 16) wout16[j * HH + k] = (j < NBI) ? f16b(W_out[j * HH + k]) : (unsigned short)0;
}

#define MFMA16(A, B, C) __builtin_amdgcn_mfma_f32_16x16x32_f16((A), (B), (C), 0, 0, 0)

__global__ __launch_bounds__(512, 2)
void lstm_main(const float* __restrict__ x,
               const float* __restrict__ b_out,
               const unsigned char* __restrict__ ws,
               float* __restrict__ out)
{
    const int j  = threadIdx.x;
    const int w  = j >> 6;        // wave 0..7 : owns gate rows [64w, 64w+64)
    const int l  = j & 63;
    const int q  = l >> 4;        // lane k-group / D row-group
    const int cb = l & 15;        // B col (batch; valid < BB) / A row within tile
    const int bbase = blockIdx.x * BB;

    const unsigned short* whh16  = (const unsigned short*)(ws + WS_WHH);
    const unsigned short* what16 = (const unsigned short*)(ws + WS_WHAT);
    const unsigned short* wihp16 = (const unsigned short*)(ws + WS_WIHP);
    const unsigned short* wout16 = (const unsigned short*)(ws + WS_WOUT);
    const float* btfp = (const float*)(ws + WS_BT);
    const float* bafp = (const float*)(ws + WS_BA);

    // padded LDS: 17-granule rows / 520-float g-stride -> every step-loop
    // access is <=2 lanes/bank (free). Pad col 16 is never written (stays 0)
    // and serves as the broadcast target for invalid batch cols.
    __shared__ half8 h_s[2][16][17];   // h state (f16), k = 8*kc + i
    __shared__ half8 x_s[2][4][17];    // x_t padded to K=32
    __shared__ float g_sf[4 * 520];    // raw gate exchange: [b][512 rows + pad]

    const int cbn = (cb < BB) ? cb : 16;

    // ---- register-resident A fragments: wave w -> tiles a=0..3, rows 64w+16a+cb ----
    half8 wf[4][4];
    half8 wxf[4];
    half8 wof[4];
    f32x4 binit[4];
#pragma unroll
    for (int a = 0; a < 4; ++a) {
        const int row = 64 * w + 16 * a + cb;
#pragma unroll
        for (int kk = 0; kk < 4; ++kk)
            wf[a][kk] = *(const half8*)(whh16 + row * HH + 32 * kk + 8 * q);
        wxf[a] = *(const half8*)(wihp16 + row * 32 + 8 * q);
#pragma unroll
        for (int r = 0; r < 4; ++r)
            binit[a][r] = btfp[64 * w + 16 * a + 4 * q + r];
    }
    const bool projw = (w == 7);
#pragma unroll
    for (int kk = 0; kk < 4; ++kk)
        wof[kk] = *(const half8*)(wout16 + cb * HH + 32 * kk + 8 * q);

    f32x4 bo4;
#pragma unroll
    for (int r = 0; r < 4; ++r) {
        const int m = 4 * q + r;
        bo4[r] = (m < NBI) ? b_out[m] : 0.0f;
    }
    const f32x4 z4 = {0.f, 0.f, 0.f, 0.f};
    float* pob = out + (size_t)(bbase + (cb & 3)) * TT * NBI;   // proj base (guarded cb<BB)

    // ---- U-phase mapping: 1 cell update per thread ----
    const int uu = j & 127;           // hidden unit
    const int ub = j >> 7;            // batch 0..3
    const float* gme = g_sf + ub * 520 + uu;

    // ---- x staging role: wave 6, 52 lanes ----
    const int  sid = j - 384;
    const bool stg = (sid >= 0) && (sid < BB * NBI);
    int s_b = 0, s_m = 0;
    const float* xp0 = x;
    float xa_h = 0.f;
    if (stg) { s_b = sid / 13; s_m = sid - 13 * s_b;
               xp0 = x + (size_t)(bbase + s_b) * TT * NBI + s_m; }

    // ---- init LDS: zero everything (pads stay 0 forever) ----
    {
        half8* hz = (half8*)h_s;              // 2*16*17 = 544 granules
        hz[j] = (half8)(_Float16)0.0f;
        if (j < 32) hz[512 + j] = (half8)(_Float16)0.0f;
        half8* xz = (half8*)x_s;              // 2*4*17 = 136 granules
        if (j < 136) xz[j] = (half8)(_Float16)0.0f;
    }
    __syncthreads();
    if (stg) {
        float v = xp0[0];                                     // x[b][0][m]
        ((_Float16*)&x_s[0][s_m >> 3][s_b])[s_m & 7] = (_Float16)v;
        out[(size_t)(bbase + s_b) * TT * NBI + s_m] = v;      // out[:,0,:] = x[:,0,:]
        xa_h = xp0[NBI];                                      // x[b][1][m]
    }
    __syncthreads();

    float c = 0.0f;        // c state pre-scaled by 2*log2e (1 per thread)
    int cur = 0;

    // ================= teacher phase: t = 0 .. T_INP =================
    for (int t = 0; t <= T_INP; ++t) {
        const int nxt = cur ^ 1;

        float xa_p = 0.f;
        if (stg && t + 2 <= T_INP) xa_p = xp0[(t + 2) * NBI];

        // ---- G phase (invalid cols broadcast the zero pad granule) ----
        half8 xf  = x_s[cur][q][cbn];
        half8 hb0 = h_s[cur][q][cbn];
        half8 hb1 = h_s[cur][4 + q][cbn];
        half8 hb2 = h_s[cur][8 + q][cbn];
        half8 hb3 = h_s[cur][12 + q][cbn];

        f32x4 a0 = MFMA16(wxf[0], xf, binit[0]);
        f32x4 a1 = MFMA16(wxf[1], xf, binit[1]);
        f32x4 a2 = MFMA16(wxf[2], xf, binit[2]);
        f32x4 a3 = MFMA16(wxf[3], xf, binit[3]);
        a0 = MFMA16(wf[0][0], hb0, a0); a1 = MFMA16(wf[1][0], hb0, a1);
        a2 = MFMA16(wf[2][0], hb0, a2); a3 = MFMA16(wf[3][0], hb0, a3);
        a0 = MFMA16(wf[0][1], hb1, a0); a1 = MFMA16(wf[1][1], hb1, a1);
        a2 = MFMA16(wf[2][1], hb1, a2); a3 = MFMA16(wf[3][1], hb1, a3);
        a0 = MFMA16(wf[0][2], hb2, a0); a1 = MFMA16(wf[1][2], hb2, a1);
        a2 = MFMA16(wf[2][2], hb2, a2); a3 = MFMA16(wf[3][2], hb2, a3);
        a0 = MFMA16(wf[0][3], hb3, a0); a1 = MFMA16(wf[1][3], hb3, a1);
        a2 = MFMA16(wf[2][3], hb3, a2); a3 = MFMA16(wf[3][3], hb3, a3);

        f32x4 pacc = z4;
        if (projw) {
            pacc = MFMA16(wof[0], hb0, z4);
            pacc = MFMA16(wof[1], hb1, pacc);
            pacc = MFMA16(wof[2], hb2, pacc);
            pacc = MFMA16(wof[3], hb3, pacc);
        }

        // raw gate exchange (stride 520 -> banks 8*cb+4*q, <=2-way)
        if (cb < BB) {
            float* gb = g_sf + cb * 520 + 64 * w + 4 * q;
            *(f32x4*)(gb)      = a0;
            *(f32x4*)(gb + 16) = a1;
            *(f32x4*)(gb + 32) = a2;
            *(f32x4*)(gb + 48) = a3;
        }
        if (projw && t >= 1 && cb < BB) {
#pragma unroll
            for (int r = 0; r < 4; ++r) {
                const int m = 4 * q + r;
                if (m < NBI) pob[t * NBI + m] = pacc[r] + bo4[r];
            }
        }
        barrier_lds();

        // ---- U phase: 1 dense cell update / thread ----
        {
            float gi = gme[0], gf = gme[128], gg = gme[256], go = gme[384];
            float ig = rcpf_(1.0f + exp2_(gi));
            float fg = rcpf_(1.0f + exp2_(gf));
            float rg = rcpf_(exp2_(gg) + 1.0f);
            float gp = C2L - C4L * rg;               // 2log2e * tanh(g)
            float og = rcpf_(1.0f + exp2_(go));
            float cn = fg * c + ig * gp;
            c = cn;
            float ec = exp2_(cn);
            float hv = og * (1.0f - 2.0f * rcpf_(ec + 1.0f));
            ((_Float16*)&h_s[nxt][uu >> 3][ub])[uu & 7] = (_Float16)hv;
        }
        if (stg && t + 1 <= T_INP) {
            ((_Float16*)&x_s[nxt][s_m >> 3][s_b])[s_m & 7] = (_Float16)xa_h;
            xa_h = xa_p;
        }
        barrier_lds();
        cur = nxt;
    }

    // ---- switch to folded weights / auto bias (uniform) ----
#pragma unroll
    for (int a = 0; a < 4; ++a) {
        const int row = 64 * w + 16 * a + cb;
#pragma unroll
        for (int kk = 0; kk < 4; ++kk)
            wf[a][kk] = *(const half8*)(what16 + row * HH + 32 * kk + 8 * q);
#pragma unroll
        for (int r = 0; r < 4; ++r)
            binit[a][r] = bafp[64 * w + 16 * a + 4 * q + r];
    }

    // ================= auto phase: t = T_INP+1 .. TT-2 =================
    for (int t = T_INP + 1; t < TT - 1; ++t) {
        const int nxt = cur ^ 1;

        half8 hb0 = h_s[cur][q][cbn];
        half8 hb1 = h_s[cur][4 + q][cbn];
        half8 hb2 = h_s[cur][8 + q][cbn];
        half8 hb3 = h_s[cur][12 + q][cbn];

        f32x4 a0 = MFMA16(wf[0][0], hb0, binit[0]);
        f32x4 a1 = MFMA16(wf[1][0], hb0, binit[1]);
        f32x4 a2 = MFMA16(wf[2][0], hb0, binit[2]);
        f32x4 a3 = MFMA16(wf[3][0], hb0, binit[3]);
        a0 = MFMA16(wf[0][1], hb1, a0); a1 = MFMA16(wf[1][1], hb1, a1);
        a2 = MFMA16(wf[2][1], hb1, a2); a3 = MFMA16(wf[3][1], hb1, a3);
        a0 = MFMA16(wf[0][2], hb2, a0); a1 = MFMA16(wf[1][2], hb2, a1);
        a2 = MFMA16(wf[2][2], hb2, a2); a3 = MFMA16(wf[3][2], hb2, a3);
        a0 = MFMA16(wf[0][3], hb3, a0); a1 = MFMA16(wf[1][3], hb3, a1);
        a2 = MFMA16(wf[2][3], hb3, a2); a3 = MFMA16(wf[3][3], hb3, a3);

        f32x4 pacc = z4;
        if (projw) {
            pacc = MFMA16(wof[0], hb0, z4);
            pacc = MFMA16(wof[1], hb1, pacc);
            pacc = MFMA16(wof[2], hb2, pacc);
            pacc = MFMA16(wof[3], hb3, pacc);
        }

        if (cb < BB) {
            float* gb = g_sf + cb * 520 + 64 * w + 4 * q;
            *(f32x4*)(gb)      = a0;
            *(f32x4*)(gb + 16) = a1;
            *(f32x4*)(gb + 32) = a2;
            *(f32x4*)(gb + 48) = a3;
        }
        if (projw && cb < BB) {
#pragma unroll
            for (int r = 0; r < 4; ++r) {
                const int m = 4 * q + r;
                if (m < NBI) pob[t * NBI + m] = pacc[r] + bo4[r];
            }
        }
        barrier_lds();

        {
            float gi = gme[0], gf = gme[128], gg = gme[256], go = gme[384];
            float ig = rcpf_(1.0f + exp2_(gi));
            float fg = rcpf_(1.0f + exp2_(gf));
            float rg = rcpf_(exp2_(gg) + 1.0f);
            float gp = C2L - C4L * rg;
            float og = rcpf_(1.0f + exp2_(go));
            float cn = fg * c + ig * gp;
            c = cn;
            float ec = exp2_(cn);
            float hv = og * (1.0f - 2.0f * rcpf_(ec + 1.0f));
            ((_Float16*)&h_s[nxt][uu >> 3][ub])[uu & 7] = (_Float16)hv;
        }
        barrier_lds();
        cur = nxt;
    }

    // ---- epilogue: out[127] = W_out h^127 + b_out ----
    if (projw) {
        half8 hb0 = h_s[cur][q][cbn];
        half8 hb1 = h_s[cur][4 + q][cbn];
        half8 hb2 = h_s[cur][8 + q][cbn];
        half8 hb3 = h_s[cur][12 + q][cbn];
        f32x4 pacc = MFMA16(wof[0], hb0, z4);
        pacc = MFMA16(wof[1], hb1, pacc);
        pacc = MFMA16(wof[2], hb2, pacc);
        pacc = MFMA16(wof[3], hb3, pacc);
        if (cb < BB) {
#pragma unroll
            for (int r = 0; r < 4; ++r) {
                const int m = 4 * q + r;
                if (m < NBI) pob[(TT - 1) * NBI + m] = pacc[r] + bo4[r];
            }
        }
    }
}

extern "C" void kernel_launch(void* const* d_in, const int* in_sizes, int n_in,
                              void* d_out, int out_size, void* d_ws, size_t ws_size,
                              hipStream_t stream)
{
    const float* x     = (const float*)d_in[0];
    const float* W_ih  = (const float*)d_in[1];
    const float* W_hh  = (const float*)d_in[2];
    const float* b_ih  = (const float*)d_in[3];
    const float* b_hh  = (const float*)d_in[4];
    const float* W_out = (const float*)d_in[5];
    const float* b_out = (const float*)d_in[6];
    float* out = (float*)d_out;
    unsigned char* ws = (unsigned char*)d_ws;

    fold_kernel<<<512, HH, 0, stream>>>(W_ih, W_hh, b_ih, b_hh, W_out, b_out, ws);
    lstm_main<<<NBLK, 512, 0, stream>>>(x, b_out, ws, out);
}